// Round 9
// baseline (276.165 us; speedup 1.0000x reference)
//
#include <hip/hip_runtime.h>

// ---------------------------------------------------------------------------
// SelfAttentionBlock: B=4, N=2048, D=1024. Single-head attention, head dim 1024.
//   QKV = X @ Wqkv^T                   (8192x1024)@(3072x1024)^T
//   E_b = exp(Q_b @ K_b^T * 0.125)     bf16 + row sums L (atomic)
//   V''_b = Wout @ V_b^T               (1024x2048) per batch
//   out_b = (E_b @ V''_b^T) / L + b    fp32
// R9: WIDE core for QKV + sv — block 128x256, 4 waves 2x2, wave tile 64x128
// (acc 2x4 f32x16): FLOP per LDS byte 32 -> 43.7. LDS-BW is the measured
// ceiling (MfmaUtil 30% == 128 MFMA-cyc / ~450-600 LDS-cyc per block-iter).
// __launch_bounds__(256,2) caps regs at 256 (2 waves/SIMD, 2 blocks/CU).
// Final GEMM (N=1024) keeps the R8 128x128 core (block count).
// BK=64, single-buffer LDS, global_load_lds w16, 8-chunk XOR swizzle.
// ---------------------------------------------------------------------------

typedef __bf16 bf16;
typedef __attribute__((ext_vector_type(8))) __bf16 bf16x8;
typedef __attribute__((ext_vector_type(4))) __bf16 bf16x4;
typedef __attribute__((ext_vector_type(16))) float f32x16;

#define BATCH 4
#define NTOK  2048
#define DIM   1024
#define MROWS (BATCH * NTOK)   // 8192
#define QKVC  (3 * DIM)        // 3072

__device__ __forceinline__ void async16(const bf16* g, bf16* l) {
  __builtin_amdgcn_global_load_lds(
      (const __attribute__((address_space(1))) void*)g,
      (__attribute__((address_space(3))) void*)l, 16, 0, 0);
}

// ---------------------------------------------------------------------------
// one prep kernel: three fp32->bf16 converts + L zero
// ---------------------------------------------------------------------------
__device__ __forceinline__ void cvt4(const float* in, bf16* out, int i4) {
  float4 f = *(const float4*)(in + i4 * 4);
  bf16x4 o;
  o.x = (bf16)f.x; o.y = (bf16)f.y; o.z = (bf16)f.z; o.w = (bf16)f.w;
  *(bf16x4*)(out + i4 * 4) = o;
}

__global__ void prep(const float* __restrict__ x, const float* __restrict__ wqkv,
                     const float* __restrict__ wout,
                     bf16* __restrict__ Xbf, bf16* __restrict__ Wqkvb,
                     bf16* __restrict__ Woutb, float* __restrict__ L) {
  const int nx = MROWS * DIM / 4, nq = QKVC * DIM / 4, nw = DIM * DIM / 4;
  const int nl = BATCH * NTOK / 4;
  int i = blockIdx.x * blockDim.x + threadIdx.x;
  if (i < nx) cvt4(x, Xbf, i);
  else if (i < nx + nq) cvt4(wqkv, Wqkvb, i - nx);
  else if (i < nx + nq + nw) cvt4(wout, Woutb, i - nx - nq);
  else if (i < nx + nq + nw + nl) {
    float4 z = {0.f, 0.f, 0.f, 0.f};
    *(float4*)(L + (i - nx - nq - nw) * 4) = z;
  }
}

// ===========================================================================
// R8 128x128 core (used by the final GEMM, N=1024).
// ===========================================================================
struct GemmCore {
  const bf16 *ga[4], *gb[4];
  int sIdx[4];
  int wm, wn, l31, half;
};

__device__ __forceinline__ GemmCore gemm_setup(const bf16* A, const bf16* Bm,
                                               int lda, int ldb,
                                               long rowA, long rowB) {
  GemmCore g;
  const int tid = threadIdx.x;
  const int wave = tid >> 6, lane = tid & 63;
  g.wm = (wave >> 1) << 6;
  g.wn = (wave & 1) << 6;
  g.l31 = lane & 31;
  g.half = lane >> 5;
  const int srow = tid >> 3;
  const int sc   = tid & 7;
  const int scol = (sc ^ (srow & 7)) << 3;
#pragma unroll
  for (int seg = 0; seg < 4; ++seg) {
    g.ga[seg] = A  + (rowA + srow + 32 * seg) * (long)lda + scol;
    g.gb[seg] = Bm + (rowB + srow + 32 * seg) * (long)ldb + scol;
    g.sIdx[seg] = (srow + 32 * seg) * 64 + sc * 8;
  }
  return g;
}

__device__ __forceinline__ void gemm_kloop(const GemmCore& g, int K,
                                           bf16* As, bf16* Bs, f32x16 acc[2][2]) {
  const int sw = g.l31 & 7;
  for (int kt = 0; kt < K; kt += 64) {
#pragma unroll
    for (int seg = 0; seg < 4; ++seg) {
      async16(g.ga[seg] + kt, As + g.sIdx[seg]);
      async16(g.gb[seg] + kt, Bs + g.sIdx[seg]);
    }
    __syncthreads();

    bf16x8 af[2][4], bfm[2][4];
#pragma unroll
    for (int ti = 0; ti < 2; ++ti)
#pragma unroll
      for (int s = 0; s < 4; ++s)
        af[ti][s] = *(const bf16x8*)&As[(g.wm + ti * 32 + g.l31) * 64 + ((s * 2 + g.half) ^ sw) * 8];
#pragma unroll
    for (int tj = 0; tj < 2; ++tj)
#pragma unroll
      for (int s = 0; s < 4; ++s)
        bfm[tj][s] = *(const bf16x8*)&Bs[(g.wn + tj * 32 + g.l31) * 64 + ((s * 2 + g.half) ^ sw) * 8];

#pragma unroll
    for (int s = 0; s < 4; ++s)
#pragma unroll
      for (int ti = 0; ti < 2; ++ti)
#pragma unroll
        for (int tj = 0; tj < 2; ++tj)
          acc[ti][tj] = __builtin_amdgcn_mfma_f32_32x32x16_bf16(
              af[ti][s], bfm[tj][s], acc[ti][tj], 0, 0, 0);

    __syncthreads();
  }
}

// final GEMM: out = E @ V''^T / L + bias, fp32
__launch_bounds__(256)
__global__ void gemm_out(const bf16* __restrict__ Eroot, const bf16* __restrict__ Vroot,
                         float* __restrict__ Croot, const float* __restrict__ bias,
                         const float* __restrict__ Lroot) {
  const bf16* A  = Eroot + (long)blockIdx.z * NTOK * NTOK;
  const bf16* Bm = Vroot + (long)blockIdx.z * DIM * NTOK;
  __shared__ alignas(16) bf16 As[128 * 64];
  __shared__ alignas(16) bf16 Bs[128 * 64];

  const long rowA = (long)blockIdx.y * 128;
  const long rowB = (long)blockIdx.x * 128;
  GemmCore g = gemm_setup(A, Bm, NTOK, NTOK, rowA, rowB);

  f32x16 acc[2][2] = {};
  gemm_kloop(g, NTOK, As, Bs, acc);

  float* C = Croot + (long)blockIdx.z * NTOK * DIM;
  const float* L = Lroot + (long)blockIdx.z * NTOK;
#pragma unroll
  for (int ti = 0; ti < 2; ++ti) {
#pragma unroll
    for (int r = 0; r < 16; ++r) {
      const long row = rowA + g.wm + ti * 32 + (r & 3) + 8 * (r >> 2) + 4 * g.half;
      const float inv = 1.0f / L[row];
#pragma unroll
      for (int tj = 0; tj < 2; ++tj) {
        const long col = rowB + g.wn + tj * 32 + g.l31;
        C[row * (long)DIM + col] = acc[ti][tj][r] * inv + bias[col];
      }
    }
  }
}

// ===========================================================================
// WIDE core: block tile 128(M) x 256(N), 4 waves 2x2, wave tile 64x128
// (acc[2][4]). LDS: A 128x64 (16KB), B 256x64 (32KB). BK=64.
// ===========================================================================
struct WCore {
  const bf16 *ga[4], *gb[8];
  int aIdx[4], bIdx[8];
  int wm, wn, l31, half;
};

__device__ __forceinline__ WCore wsetup(const bf16* A, const bf16* Bm,
                                        int lda, int ldb,
                                        long rowA, long rowB) {
  WCore g;
  const int tid = threadIdx.x;
  const int wave = tid >> 6, lane = tid & 63;
  g.wm = (wave >> 1) << 6;          // 0 or 64
  g.wn = (wave & 1) << 7;           // 0 or 128
  g.l31 = lane & 31;
  g.half = lane >> 5;
  const int srow = tid >> 3;               // 0..31
  const int sc   = tid & 7;
  const int scol = (sc ^ (srow & 7)) << 3;
#pragma unroll
  for (int seg = 0; seg < 4; ++seg) {
    g.ga[seg] = A + (rowA + srow + 32 * seg) * (long)lda + scol;
    g.aIdx[seg] = (srow + 32 * seg) * 64 + sc * 8;
  }
#pragma unroll
  for (int seg = 0; seg < 8; ++seg) {
    g.gb[seg] = Bm + (rowB + srow + 32 * seg) * (long)ldb + scol;
    g.bIdx[seg] = (srow + 32 * seg) * 64 + sc * 8;
  }
  return g;
}

__device__ __forceinline__ void wkloop(const WCore& g, int K,
                                       bf16* As, bf16* Bs, f32x16 acc[2][4]) {
  const int sw = g.l31 & 7;
  for (int kt = 0; kt < K; kt += 64) {
#pragma unroll
    for (int seg = 0; seg < 4; ++seg) async16(g.ga[seg] + kt, As + g.aIdx[seg]);
#pragma unroll
    for (int seg = 0; seg < 8; ++seg) async16(g.gb[seg] + kt, Bs + g.bIdx[seg]);
    __syncthreads();

#pragma unroll
    for (int s = 0; s < 4; ++s) {
      bf16x8 af[2], bfm[4];
#pragma unroll
      for (int ti = 0; ti < 2; ++ti)
        af[ti] = *(const bf16x8*)&As[(g.wm + ti * 32 + g.l31) * 64 + ((s * 2 + g.half) ^ sw) * 8];
#pragma unroll
      for (int tj = 0; tj < 4; ++tj)
        bfm[tj] = *(const bf16x8*)&Bs[(g.wn + tj * 32 + g.l31) * 64 + ((s * 2 + g.half) ^ sw) * 8];
#pragma unroll
      for (int ti = 0; ti < 2; ++ti)
#pragma unroll
        for (int tj = 0; tj < 4; ++tj)
          acc[ti][tj] = __builtin_amdgcn_mfma_f32_32x32x16_bf16(
              af[ti], bfm[tj], acc[ti][tj], 0, 0, 0);
    }
    __syncthreads();
  }
}

// QKV GEMM (wide): C = A @ B^T -> bf16
__launch_bounds__(256, 2)
__global__ void gemm_qkv(const bf16* __restrict__ A, const bf16* __restrict__ B,
                         bf16* __restrict__ C) {
  __shared__ alignas(16) bf16 As[128 * 64];
  __shared__ alignas(16) bf16 Bs[256 * 64];
  const long rowA = (long)blockIdx.y * 128;
  const long rowB = (long)blockIdx.x * 256;
  WCore g = wsetup(A, B, DIM, DIM, rowA, rowB);
  f32x16 acc[2][4] = {};
  wkloop(g, DIM, As, Bs, acc);

#pragma unroll
  for (int ti = 0; ti < 2; ++ti)
#pragma unroll
    for (int tj = 0; tj < 4; ++tj) {
      const long col = rowB + g.wn + tj * 32 + g.l31;
#pragma unroll
      for (int r = 0; r < 16; ++r) {
        const long row = rowA + g.wm + ti * 32 + (r & 3) + 8 * (r >> 2) + 4 * g.half;
        C[row * (long)QKVC + col] = (bf16)acc[ti][tj][r];
      }
    }
}

// Fused sv (wide): z<4 -> E_b = exp(Q@K^T/8) + L; z>=4 -> V'' = Wout @ V^T
__launch_bounds__(256, 2)
__global__ void gemm_sv(const bf16* __restrict__ QKV, const bf16* __restrict__ Wout,
                        bf16* __restrict__ E, bf16* __restrict__ Vpp,
                        float* __restrict__ Lroot) {
  __shared__ alignas(16) bf16 As[128 * 64];
  __shared__ alignas(16) bf16 Bs[256 * 64];

  const int z = blockIdx.z;
  if (z < 4) {
    const bf16* A  = QKV + (long)z * NTOK * QKVC;
    const bf16* Bm = A + DIM;
    const long rowA = (long)blockIdx.y * 128;
    const long rowB = (long)blockIdx.x * 256;
    WCore g = wsetup(A, Bm, QKVC, QKVC, rowA, rowB);
    f32x16 acc[2][4] = {};
    wkloop(g, DIM, As, Bs, acc);

    bf16* C = E + (long)z * NTOK * NTOK;
    float* L = Lroot + (long)z * NTOK;
#pragma unroll
    for (int ti = 0; ti < 2; ++ti) {
#pragma unroll
      for (int r = 0; r < 16; ++r) {
        const long row = rowA + g.wm + ti * 32 + (r & 3) + 8 * (r >> 2) + 4 * g.half;
        float psum = 0.f;
#pragma unroll
        for (int tj = 0; tj < 4; ++tj) {
          const long col = rowB + g.wn + tj * 32 + g.l31;
          float e = __expf(acc[ti][tj][r] * 0.125f);
          bf16 eb = (bf16)e;
          C[row * (long)NTOK + col] = eb;
          psum += (float)eb;
        }
#pragma unroll
        for (int off = 16; off >= 1; off >>= 1) psum += __shfl_xor(psum, off, 64);
        if (g.l31 == 0) atomicAdd(&L[row], psum);
      }
    }
  } else {
    if (blockIdx.y >= 8) return;   // V'' has 1024 rows = 8 row-tiles
    const int b = z - 4;
    const bf16* Bm = QKV + (long)b * NTOK * QKVC + 2 * DIM;
    const long rowA = (long)blockIdx.y * 128;
    const long rowB = (long)blockIdx.x * 256;
    WCore g = wsetup(Wout, Bm, DIM, QKVC, rowA, rowB);
    f32x16 acc[2][4] = {};
    wkloop(g, DIM, As, Bs, acc);

    bf16* C = Vpp + (long)b * DIM * NTOK;
#pragma unroll
    for (int ti = 0; ti < 2; ++ti)
#pragma unroll
      for (int tj = 0; tj < 4; ++tj) {
        const long col = rowB + g.wn + tj * 32 + g.l31;
#pragma unroll
        for (int r = 0; r < 16; ++r) {
          const long row = rowA + g.wm + ti * 32 + (r & 3) + 8 * (r >> 2) + 4 * g.half;
          C[row * (long)NTOK + col] = (bf16)acc[ti][tj][r];
        }
      }
  }
}

// ---------------------------------------------------------------------------
extern "C" void kernel_launch(void* const* d_in, const int* in_sizes, int n_in,
                              void* d_out, int out_size, void* d_ws, size_t ws_size,
                              hipStream_t stream) {
  const float* x      = (const float*)d_in[0];
  const float* w_qkv  = (const float*)d_in[1];
  const float* w_out  = (const float*)d_in[2];
  const float* b_out  = (const float*)d_in[3];
  float* out = (float*)d_out;

  char* w = (char*)d_ws;
  bf16*  Xbf   = (bf16*)(w);                          // 16 MiB
  bf16*  Wqkvb = (bf16*)(w + 16777216);               //  6 MiB
  bf16*  Woutb = (bf16*)(w + 23068672);               //  2 MiB
  bf16*  QKV   = (bf16*)(w + 25165824);               // 48 MiB
  bf16*  E     = (bf16*)(w + 75497472);               // 32 MiB
  bf16*  Vpp   = (bf16*)(w + 109051904);              // 16 MiB
  float* L     = (float*)(w + 125829120);             // 32 KiB

  // 1) prep: converts + L zero
  {
    const int n4 = MROWS * DIM / 4 + QKVC * DIM / 4 + DIM * DIM / 4 + BATCH * NTOK / 4;
    prep<<<(n4 + 255) / 256, 256, 0, stream>>>(x, w_qkv, w_out, Xbf, Wqkvb, Woutb, L);
  }

  // 2) QKV = X @ Wqkv^T -> bf16 (8192 x 3072), wide core
  gemm_qkv<<<dim3(QKVC / 256, MROWS / 128, 1), 256, 0, stream>>>(Xbf, Wqkvb, QKV);

  // 3) fused: E_b = exp(Q@K^T/8) + L  AND  V'' = Wout @ V^T, wide core
  gemm_sv<<<dim3(NTOK / 256, NTOK / 128, 2 * BATCH), 256, 0, stream>>>(
      QKV, Woutb, E, Vpp, L);

  // 4) out = E @ V''^T / L + bias -> fp32, R8 core
  gemm_out<<<dim3(DIM / 128, NTOK / 128, BATCH), 256, 0, stream>>>(
      E, Vpp, out, b_out, L);
}